// Round 3
// baseline (1881.907 us; speedup 1.0000x reference)
//
#include <hip/hip_runtime.h>

// DGM forward, MI355X. bf16 MFMA 16x16x32, fp32 accum, fp32 tanh.
// R3: 512-thread WG, M=64 rows/WG; wave w owns cols [w*32, w*32+32) (2 col-blocks).
//     K extended 256->288: X@U folded into MFMA (pack kernel appends U rows + zeros).
//     One f32 accumulator set live at a time; S mirrored in packed bf16 regs (sreg).
//     LDS = Sb(32K) + S1b(32K) -> 2 WGs/CU = 16 waves/CU.
//
// MFMA 16x16x32 layouts (ln = lane, q = ln>>4, c15 = ln&15):
//  A-frag: lane holds A[m=c15][k=kb*32+q*8+i], i=0..7
//  B-frag: lane holds B[k=kb*32+q*8+i][n=cblk*16+c15]
//  C/D:    lane holds C[row=q*4+ii][col=c15]
// Packed W (d_ws): idx = (((mat*16+cblk)*9+kb)*64+ln)*8+i, mat = l*4+gate, kb=8 holds U/0.
// LDS state swizzle: elem(r,k) -> r*256 + (((k>>3)^r)&31)*8 + (k&7)

typedef __attribute__((ext_vector_type(8))) short bf16x8;
typedef __attribute__((ext_vector_type(4))) float f32x4;

__device__ __forceinline__ short f2bf(float f) {
    unsigned u = __float_as_uint(f);
    unsigned r = (u + 0x7FFFu + ((u >> 16) & 1u)) >> 16;
    return (short)r;
}
__device__ __forceinline__ float bf2f(short h) {
    return __uint_as_float(((unsigned)(unsigned short)h) << 16);
}
__device__ __forceinline__ float fast_tanh(float x) {
    float e = __expf(2.0f * x);
    return 1.0f - 2.0f * __builtin_amdgcn_rcpf(e + 1.0f);
}
__device__ __forceinline__ int sw_off(int r, int k) {
    return r * 256 + ((((k >> 3) ^ r) & 31) << 3) + (k & 7);
}
__device__ __forceinline__ unsigned pk2(float a, float b) {
    return (unsigned)(unsigned short)f2bf(a) | ((unsigned)(unsigned short)f2bf(b) << 16);
}
__device__ __forceinline__ float upk(unsigned p, int hi) {
    return __uint_as_float(hi ? (p & 0xFFFF0000u) : (p << 16));
}

// ---------------- pack weights fp32 -> bf16, B-frag order, K=288 ----------------
__global__ void pack_w(const float* __restrict__ Wz, const float* __restrict__ Wg,
                       const float* __restrict__ Wr, const float* __restrict__ Wh,
                       const float* __restrict__ Uz, const float* __restrict__ Ug,
                       const float* __restrict__ Ur, const float* __restrict__ Uh,
                       short* __restrict__ out) {
    int idx = blockIdx.x * 256 + threadIdx.x;     // 884736 threads
    int i  = idx & 7;
    int ln = (idx >> 3) & 63;
    int t  = idx >> 9;                            // (mat*16+cblk)*9+kb
    int kb = t % 9;
    int t2 = t / 9;
    int cblk = t2 & 15;
    int mat  = t2 >> 4;                           // 0..11 = l*4+g
    int l = mat >> 2, g = mat & 3;
    int n = cblk * 16 + (ln & 15);
    int j = ((ln >> 4) << 3) + i;                 // 0..31 within K-chunk
    const float* W = (g == 0) ? Wz : (g == 1) ? Wg : (g == 2) ? Wr : Wh;
    const float* U = (g == 0) ? Uz : (g == 1) ? Ug : (g == 2) ? Ur : Uh;
    float v;
    if (kb < 8) v = W[l * 65536 + (kb * 32 + j) * 256 + n];
    else        v = (j < 2) ? U[l * 512 + j * 256 + n] : 0.0f;
    out[idx] = f2bf(v);
}

// ---------------- one gate GEMM: acc = bias + [X|In] @ [U;W] ----------------
__device__ __forceinline__ void gate_gemm(const short* __restrict__ In,   // LDS [64][256] swizzled
                                          const short* __restrict__ Wm,   // packed bf16, 73728
                                          const float* __restrict__ bias, // [256]
                                          const unsigned txp[4],
                                          int q, int c15, int w, int ln,
                                          f32x4 acc[4][2]) {
#pragma unroll
    for (int cb = 0; cb < 2; cb++) {
        float bb = bias[(w * 2 + cb) * 16 + c15];
#pragma unroll
        for (int rb = 0; rb < 4; rb++)
#pragma unroll
            for (int ii = 0; ii < 4; ii++)
                acc[rb][cb][ii] = bb;
    }
#pragma unroll
    for (int kb = 0; kb < 8; kb++) {
        bf16x8 a[4];
#pragma unroll
        for (int rb = 0; rb < 4; rb++) {
            int r = rb * 16 + c15;
            a[rb] = *(const bf16x8*)(In + r * 256 + ((((kb * 4 + q) ^ r) & 31) << 3));
        }
#pragma unroll
        for (int cb = 0; cb < 2; cb++) {
            bf16x8 b = *(const bf16x8*)(Wm + ((((w * 2 + cb) * 9 + kb) * 64 + ln) << 3));
#pragma unroll
            for (int rb = 0; rb < 4; rb++)
                acc[rb][cb] = __builtin_amdgcn_mfma_f32_16x16x32_bf16(a[rb], b, acc[rb][cb], 0, 0, 0);
        }
    }
    // kb=8: folded X@U. A_ext rows = [t, x, 0...]: only q==0 lanes nonzero.
#pragma unroll
    for (int cb = 0; cb < 2; cb++) {
        bf16x8 b = *(const bf16x8*)(Wm + ((((w * 2 + cb) * 9 + 8) * 64 + ln) << 3));
#pragma unroll
        for (int rb = 0; rb < 4; rb++) {
            bf16x8 a8 = {0, 0, 0, 0, 0, 0, 0, 0};
            if (q == 0) {
                a8[0] = (short)(txp[rb] & 0xFFFFu);
                a8[1] = (short)(txp[rb] >> 16);
            }
            acc[rb][cb] = __builtin_amdgcn_mfma_f32_16x16x32_bf16(a8, b, acc[rb][cb], 0, 0, 0);
        }
    }
}

// ---------------- main kernel: 64 rows/WG, 512 threads ----------------
__global__ __launch_bounds__(512, 4)
void dgm_main(const float* __restrict__ T, const float* __restrict__ X,
              const float* __restrict__ W0, const float* __restrict__ b0,
              const float* __restrict__ bz, const float* __restrict__ bg,
              const float* __restrict__ br, const float* __restrict__ bh,
              const float* __restrict__ Wf, const float* __restrict__ bfp,
              const short* __restrict__ Wp, float* __restrict__ out) {
    __shared__ __align__(16) short Sb[16384];    // 32 KB: S (holds S*R mid-layer)
    __shared__ __align__(16) short S1b[16384];   // 32 KB: S1, immutable
    __shared__ float2 txS[64];

    const int tid = threadIdx.x;
    const int w   = tid >> 6;        // 0..7
    const int ln  = tid & 63;
    const int q   = ln >> 4;
    const int c15 = ln & 15;
    const int m0  = blockIdx.x * 64;

    if (tid < 64) txS[tid] = make_float2(T[m0 + tid], X[m0 + tid]);
    __syncthreads();

    // ---- S1 = tanh(X@W0 + b0); S = S1 ----
    {
        int col = tid & 255;
        int r0  = (tid >> 8) << 5;
        float w00 = W0[col], w01 = W0[256 + col], bb = b0[col];
#pragma unroll 4
        for (int rr = 0; rr < 32; rr++) {
            int r = r0 + rr;
            float2 tx = txS[r];
            short v = f2bf(fast_tanh(tx.x * w00 + tx.y * w01 + bb));
            int off = sw_off(r, col);
            S1b[off] = v;
            Sb[off]  = v;
        }
    }
    __syncthreads();

    // packed [t,x] per row-block for the K-extension A-fragment (row = rb*16+c15)
    unsigned txp[4];
#pragma unroll
    for (int rb = 0; rb < 4; rb++) {
        float2 tx = txS[rb * 16 + c15];
        txp[rb] = pk2(tx.x, tx.y);
    }

    // register mirror of this thread's owned S elements (C-layout), packed bf16
    unsigned sreg[4][2][2];
#pragma unroll
    for (int rb = 0; rb < 4; rb++)
#pragma unroll
        for (int cb = 0; cb < 2; cb++) {
            int col = (w * 2 + cb) * 16 + c15;
#pragma unroll
            for (int p = 0; p < 2; p++) {
                unsigned lo = (unsigned short)Sb[sw_off(rb * 16 + q * 4 + 2 * p,     col)];
                unsigned hi = (unsigned short)Sb[sw_off(rb * 16 + q * 4 + 2 * p + 1, col)];
                sreg[rb][cb][p] = lo | (hi << 16);
            }
        }

    // ---- layers ----
    for (int l = 0; l < 3; l++) {
        const short* Wzp = Wp + (l * 4 + 0) * 73728;
        const short* Wgp = Wp + (l * 4 + 1) * 73728;
        const short* Wrp = Wp + (l * 4 + 2) * 73728;
        const short* Whp = Wp + (l * 4 + 3) * 73728;

        f32x4 acc[4][2];
        unsigned zsp[4][2][2], srp[4][2][2], gmp[4][2][2];

        // Z gate: zs = tanh(Z)*S_old
        gate_gemm(Sb, Wzp, bz + l * 256, txp, q, c15, w, ln, acc);
#pragma unroll
        for (int rb = 0; rb < 4; rb++)
#pragma unroll
            for (int cb = 0; cb < 2; cb++)
#pragma unroll
                for (int p = 0; p < 2; p++)
                    zsp[rb][cb][p] = pk2(
                        fast_tanh(acc[rb][cb][2 * p])     * upk(sreg[rb][cb][p], 0),
                        fast_tanh(acc[rb][cb][2 * p + 1]) * upk(sreg[rb][cb][p], 1));

        // R gate: sr = S_old*tanh(R)
        gate_gemm(Sb, Wrp, br + l * 256, txp, q, c15, w, ln, acc);
#pragma unroll
        for (int rb = 0; rb < 4; rb++)
#pragma unroll
            for (int cb = 0; cb < 2; cb++)
#pragma unroll
                for (int p = 0; p < 2; p++)
                    srp[rb][cb][p] = pk2(
                        fast_tanh(acc[rb][cb][2 * p])     * upk(sreg[rb][cb][p], 0),
                        fast_tanh(acc[rb][cb][2 * p + 1]) * upk(sreg[rb][cb][p], 1));

        __syncthreads();   // B1: all Sb reads (Z,R A-frags) done
#pragma unroll
        for (int rb = 0; rb < 4; rb++)
#pragma unroll
            for (int cb = 0; cb < 2; cb++) {
                int col = (w * 2 + cb) * 16 + c15;
#pragma unroll
                for (int p = 0; p < 2; p++) {
                    Sb[sw_off(rb * 16 + q * 4 + 2 * p,     col)] = (short)(srp[rb][cb][p] & 0xFFFFu);
                    Sb[sw_off(rb * 16 + q * 4 + 2 * p + 1, col)] = (short)(srp[rb][cb][p] >> 16);
                }
            }

        // G gate (reads only S1b) — overlaps the Sb-write window
        gate_gemm(S1b, Wgp, bg + l * 256, txp, q, c15, w, ln, acc);
#pragma unroll
        for (int rb = 0; rb < 4; rb++)
#pragma unroll
            for (int cb = 0; cb < 2; cb++)
#pragma unroll
                for (int p = 0; p < 2; p++)
                    gmp[rb][cb][p] = pk2(1.0f - fast_tanh(acc[rb][cb][2 * p]),
                                         1.0f - fast_tanh(acc[rb][cb][2 * p + 1]));

        __syncthreads();   // B2: Sb = S*R visible

        // H gate (reads Sb = S*R)
        gate_gemm(Sb, Whp, bh + l * 256, txp, q, c15, w, ln, acc);

        // S_new = (1-G)*tanh(H) + zs   (compute before B3; no Sb access here)
#pragma unroll
        for (int rb = 0; rb < 4; rb++)
#pragma unroll
            for (int cb = 0; cb < 2; cb++)
#pragma unroll
                for (int p = 0; p < 2; p++) {
                    float sn0 = upk(gmp[rb][cb][p], 0) * fast_tanh(acc[rb][cb][2 * p])
                              + upk(zsp[rb][cb][p], 0);
                    float sn1 = upk(gmp[rb][cb][p], 1) * fast_tanh(acc[rb][cb][2 * p + 1])
                              + upk(zsp[rb][cb][p], 1);
                    srp[rb][cb][p] = pk2(sn0, sn1);
                }

        __syncthreads();   // B3: all H A-frag reads of Sb done
#pragma unroll
        for (int rb = 0; rb < 4; rb++)
#pragma unroll
            for (int cb = 0; cb < 2; cb++) {
                int col = (w * 2 + cb) * 16 + c15;
#pragma unroll
                for (int p = 0; p < 2; p++) {
                    Sb[sw_off(rb * 16 + q * 4 + 2 * p,     col)] = (short)(srp[rb][cb][p] & 0xFFFFu);
                    Sb[sw_off(rb * 16 + q * 4 + 2 * p + 1, col)] = (short)(srp[rb][cb][p] >> 16);
                    sreg[rb][cb][p] = srp[rb][cb][p];
                }
            }
        __syncthreads();   // B4: new S visible
    }

    // ---- out = S @ Wf + bf : 8 threads/row, vectorized LDS reads ----
    {
        int row = tid >> 3;
        int seg = tid & 7;
        float sum = 0.0f;
#pragma unroll
        for (int j = 0; j < 4; j++) {
            int ch = seg * 4 + j;
            bf16x8 sv = *(const bf16x8*)(Sb + row * 256 + (((ch ^ row) & 31) << 3));
            float4 wa = *(const float4*)(Wf + ch * 8);
            float4 wb = *(const float4*)(Wf + ch * 8 + 4);
            sum += bf2f(sv[0]) * wa.x + bf2f(sv[1]) * wa.y + bf2f(sv[2]) * wa.z + bf2f(sv[3]) * wa.w
                 + bf2f(sv[4]) * wb.x + bf2f(sv[5]) * wb.y + bf2f(sv[6]) * wb.z + bf2f(sv[7]) * wb.w;
        }
        sum += __shfl_down(sum, 4, 8);
        sum += __shfl_down(sum, 2, 8);
        sum += __shfl_down(sum, 1, 8);
        if (seg == 0) out[m0 + row] = sum + bfp[0];
    }
}

extern "C" void kernel_launch(void* const* d_in, const int* in_sizes, int n_in,
                              void* d_out, int out_size, void* d_ws, size_t ws_size,
                              hipStream_t stream) {
    const float* T  = (const float*)d_in[0];
    const float* X  = (const float*)d_in[1];
    const float* W0 = (const float*)d_in[2];
    const float* b0 = (const float*)d_in[3];
    const float* Uz = (const float*)d_in[4];
    const float* Ug = (const float*)d_in[5];
    const float* Ur = (const float*)d_in[6];
    const float* Uh = (const float*)d_in[7];
    const float* Wz = (const float*)d_in[8];
    const float* Wg = (const float*)d_in[9];
    const float* Wr = (const float*)d_in[10];
    const float* Wh = (const float*)d_in[11];
    const float* bz = (const float*)d_in[12];
    const float* bg = (const float*)d_in[13];
    const float* br = (const float*)d_in[14];
    const float* bh = (const float*)d_in[15];
    const float* Wf = (const float*)d_in[16];
    const float* bfp= (const float*)d_in[17];
    float* out = (float*)d_out;
    short* Wp = (short*)d_ws;           // 12*73728 bf16 = 1.73 MB
    const int N = in_sizes[0];

    pack_w<<<3456, 256, 0, stream>>>(Wz, Wg, Wr, Wh, Uz, Ug, Ur, Uh, Wp);
    dgm_main<<<N / 64, 512, 0, stream>>>(T, X, W0, b0, bz, bg, br, bh, Wf, bfp, Wp, out);
}

// Round 4
// 1363.987 us; speedup vs baseline: 1.3797x; 1.3797x over previous
//
#include <hip/hip_runtime.h>

// DGM forward, MI355X. bf16 MFMA 16x16x32, fp32 accum, fp32 tanh.
// R4: R1 structure (M=32/WG, 256 thr, wave w owns cols [w*64,w*64+64)) with:
//     - SRb eliminated via zs = Z*S_old trick -> LDS = Sb(16K)+S1b(16K)+eps = 33KB
//       -> 4 WGs/CU (16 waves/CU), launch_bounds(256,4) => VGPR cap 128 (blocks/CU semantics!)
//     - sreg: packed bf16 register mirror of owned S elements (no scalar LDS reads in epilogues)
//     - gate order Z, R, G(S1b-only) before B1; one f32 acc set live at a time
//
// MFMA 16x16x32 layouts (ln = lane, q = ln>>4, c15 = ln&15):
//  A-frag: lane holds A[m=c15][k=kb*32+q*8+i], i=0..7
//  B-frag: lane holds B[k=kb*32+q*8+i][n=cblk*16+c15]
//  C/D:    lane holds C[row=q*4+ii][col=c15]
// W packed (d_ws) B-frag order per matrix: idx = (((cblk*8+kb)*64+ln)*8+i)
// LDS state swizzle: elem(r,k) -> r*256 + (((k>>3)^r)&31)*8 + (k&7)

typedef __attribute__((ext_vector_type(8))) short bf16x8;
typedef __attribute__((ext_vector_type(4))) float f32x4;

__device__ __forceinline__ short f2bf(float f) {
    unsigned u = __float_as_uint(f);
    unsigned r = (u + 0x7FFFu + ((u >> 16) & 1u)) >> 16;
    return (short)r;
}
__device__ __forceinline__ float bf2f(short h) {
    return __uint_as_float(((unsigned)(unsigned short)h) << 16);
}
__device__ __forceinline__ float fast_tanh(float x) {
    float e = __expf(2.0f * x);
    return 1.0f - 2.0f * __builtin_amdgcn_rcpf(e + 1.0f);
}
__device__ __forceinline__ int sw_off(int r, int k) {
    return r * 256 + ((((k >> 3) ^ r) & 31) << 3) + (k & 7);
}
__device__ __forceinline__ unsigned pk2(float a, float b) {
    return (unsigned)(unsigned short)f2bf(a) | ((unsigned)(unsigned short)f2bf(b) << 16);
}
__device__ __forceinline__ float upk(unsigned p, int hi) {
    return __uint_as_float(hi ? (p & 0xFFFF0000u) : (p << 16));
}

// ---------------- pack weights fp32 -> bf16, B-frag order (R1 version) ----------------
__global__ void pack_w(const float* __restrict__ Wz, const float* __restrict__ Wg,
                       const float* __restrict__ Wr, const float* __restrict__ Wh,
                       short* __restrict__ out) {
    int idx = blockIdx.x * 256 + threadIdx.x;   // 12*65536 threads
    int mat = idx >> 16;                        // 0..11 = l*4+g
    int e   = idx & 65535;
    int l = mat >> 2, g = mat & 3;
    int i  = e & 7;
    int ln = (e >> 3) & 63;
    int kb = (e >> 9) & 7;
    int c  = e >> 12;
    int k = kb * 32 + (ln >> 4) * 8 + i;
    int n = c * 16 + (ln & 15);
    const float* W = (g == 0) ? Wz : (g == 1) ? Wg : (g == 2) ? Wr : Wh;
    out[idx] = f2bf(W[l * 65536 + k * 256 + n]);
}

// ---------------- one gate GEMM: acc = bias + X@U + In@W ----------------
__device__ __forceinline__ void gate_gemm(const short* __restrict__ In,   // LDS [32][256] swizzled
                                          const short* __restrict__ Wm,   // packed bf16 65536
                                          const float* __restrict__ U,    // [2][256] fp32
                                          const float* __restrict__ bias, // [256]
                                          const float2* __restrict__ txS, // LDS [32]
                                          int q, int c15, int w,
                                          f32x4 acc[2][4]) {
    float2 tx[8];
#pragma unroll
    for (int rb = 0; rb < 2; rb++)
#pragma unroll
        for (int ii = 0; ii < 4; ii++) tx[rb * 4 + ii] = txS[rb * 16 + q * 4 + ii];
#pragma unroll
    for (int cb = 0; cb < 4; cb++) {
        int col = (w * 4 + cb) * 16 + c15;
        float u0 = U[col], u1 = U[256 + col], bb = bias[col];
#pragma unroll
        for (int rb = 0; rb < 2; rb++)
#pragma unroll
            for (int ii = 0; ii < 4; ii++)
                acc[rb][cb][ii] = bb + tx[rb * 4 + ii].x * u0 + tx[rb * 4 + ii].y * u1;
    }
#pragma unroll
    for (int kb = 0; kb < 8; kb++) {
        bf16x8 a[2];
#pragma unroll
        for (int rb = 0; rb < 2; rb++) {
            int r = rb * 16 + c15;
            a[rb] = *(const bf16x8*)(In + r * 256 + ((((kb * 4 + q) ^ r) & 31) << 3));
        }
#pragma unroll
        for (int cb = 0; cb < 4; cb++) {
            bf16x8 b = *(const bf16x8*)(Wm + ((((w * 4 + cb) * 8 + kb) * 64 + (q * 16 + c15)) << 3));
#pragma unroll
            for (int rb = 0; rb < 2; rb++)
                acc[rb][cb] = __builtin_amdgcn_mfma_f32_16x16x32_bf16(a[rb], b, acc[rb][cb], 0, 0, 0);
        }
    }
}

// ---------------- main kernel: 32 rows/WG, 256 threads ----------------
__global__ __launch_bounds__(256, 4)
void dgm_main(const float* __restrict__ T, const float* __restrict__ X,
              const float* __restrict__ W0, const float* __restrict__ b0,
              const float* __restrict__ Uz, const float* __restrict__ Ug,
              const float* __restrict__ Ur, const float* __restrict__ Uh,
              const float* __restrict__ bz, const float* __restrict__ bg,
              const float* __restrict__ br, const float* __restrict__ bh,
              const float* __restrict__ Wf, const float* __restrict__ bfp,
              const short* __restrict__ Wp, float* __restrict__ out) {
    __shared__ __align__(16) short Sb[8192];    // 16 KB: S (holds S*R mid-layer)
    __shared__ __align__(16) short S1b[8192];   // 16 KB: S1, immutable
    __shared__ float2 txS[32];

    const int tid = threadIdx.x;
    const int w   = tid >> 6;        // 0..3
    const int ln  = tid & 63;
    const int q   = ln >> 4;
    const int c15 = ln & 15;
    const int m0  = blockIdx.x * 32;

    if (tid < 32) txS[tid] = make_float2(T[m0 + tid], X[m0 + tid]);
    __syncthreads();

    // ---- S1 = tanh(X@W0 + b0); S = S1.  One column per thread, 32 rows. ----
    {
        float w00 = W0[tid], w01 = W0[256 + tid], bb = b0[tid];
#pragma unroll 4
        for (int r = 0; r < 32; r++) {
            float2 tx = txS[r];
            short v = f2bf(fast_tanh(tx.x * w00 + tx.y * w01 + bb));
            int off = sw_off(r, tid);
            S1b[off] = v;
            Sb[off]  = v;
        }
    }
    __syncthreads();

    // register mirror of this thread's owned S elements (C-layout), packed bf16
    unsigned sreg[2][4][2];
#pragma unroll
    for (int rb = 0; rb < 2; rb++)
#pragma unroll
        for (int cb = 0; cb < 4; cb++) {
            int col = (w * 4 + cb) * 16 + c15;
#pragma unroll
            for (int p = 0; p < 2; p++) {
                unsigned lo = (unsigned short)Sb[sw_off(rb * 16 + q * 4 + 2 * p,     col)];
                unsigned hi = (unsigned short)Sb[sw_off(rb * 16 + q * 4 + 2 * p + 1, col)];
                sreg[rb][cb][p] = lo | (hi << 16);
            }
        }

    // ---- layers ----
    for (int l = 0; l < 3; l++) {
        const short* Wzp = Wp + (l * 4 + 0) * 65536;
        const short* Wgp = Wp + (l * 4 + 1) * 65536;
        const short* Wrp = Wp + (l * 4 + 2) * 65536;
        const short* Whp = Wp + (l * 4 + 3) * 65536;

        f32x4 acc[2][4];
        unsigned zsp[2][4][2], srp[2][4][2], gmp[2][4][2];

        // Z gate: zs = tanh(Z)*S_old
        gate_gemm(Sb, Wzp, Uz + l * 512, bz + l * 256, txS, q, c15, w, acc);
#pragma unroll
        for (int rb = 0; rb < 2; rb++)
#pragma unroll
            for (int cb = 0; cb < 4; cb++)
#pragma unroll
                for (int p = 0; p < 2; p++)
                    zsp[rb][cb][p] = pk2(
                        fast_tanh(acc[rb][cb][2 * p])     * upk(sreg[rb][cb][p], 0),
                        fast_tanh(acc[rb][cb][2 * p + 1]) * upk(sreg[rb][cb][p], 1));

        // R gate: sr = S_old*tanh(R)
        gate_gemm(Sb, Wrp, Ur + l * 512, br + l * 256, txS, q, c15, w, acc);
#pragma unroll
        for (int rb = 0; rb < 2; rb++)
#pragma unroll
            for (int cb = 0; cb < 4; cb++)
#pragma unroll
                for (int p = 0; p < 2; p++)
                    srp[rb][cb][p] = pk2(
                        fast_tanh(acc[rb][cb][2 * p])     * upk(sreg[rb][cb][p], 0),
                        fast_tanh(acc[rb][cb][2 * p + 1]) * upk(sreg[rb][cb][p], 1));

        // G gate (reads only S1b)
        gate_gemm(S1b, Wgp, Ug + l * 512, bg + l * 256, txS, q, c15, w, acc);
#pragma unroll
        for (int rb = 0; rb < 2; rb++)
#pragma unroll
            for (int cb = 0; cb < 4; cb++)
#pragma unroll
                for (int p = 0; p < 2; p++)
                    gmp[rb][cb][p] = pk2(1.0f - fast_tanh(acc[rb][cb][2 * p]),
                                         1.0f - fast_tanh(acc[rb][cb][2 * p + 1]));

        __syncthreads();   // B1: all Sb reads (Z,R A-frags) done
#pragma unroll
        for (int rb = 0; rb < 2; rb++)
#pragma unroll
            for (int cb = 0; cb < 4; cb++) {
                int col = (w * 4 + cb) * 16 + c15;
#pragma unroll
                for (int p = 0; p < 2; p++) {
                    Sb[sw_off(rb * 16 + q * 4 + 2 * p,     col)] = (short)(srp[rb][cb][p] & 0xFFFFu);
                    Sb[sw_off(rb * 16 + q * 4 + 2 * p + 1, col)] = (short)(srp[rb][cb][p] >> 16);
                }
            }
        __syncthreads();   // B2: Sb = S*R visible

        // H gate (reads Sb = S*R)
        gate_gemm(Sb, Whp, Uh + l * 512, bh + l * 256, txS, q, c15, w, acc);

        // S_new = (1-G)*tanh(H) + zs  (no Sb access here)
#pragma unroll
        for (int rb = 0; rb < 2; rb++)
#pragma unroll
            for (int cb = 0; cb < 4; cb++)
#pragma unroll
                for (int p = 0; p < 2; p++) {
                    float sn0 = upk(gmp[rb][cb][p], 0) * fast_tanh(acc[rb][cb][2 * p])
                              + upk(zsp[rb][cb][p], 0);
                    float sn1 = upk(gmp[rb][cb][p], 1) * fast_tanh(acc[rb][cb][2 * p + 1])
                              + upk(zsp[rb][cb][p], 1);
                    srp[rb][cb][p] = pk2(sn0, sn1);
                }

        __syncthreads();   // B3: all H A-frag reads of Sb done
#pragma unroll
        for (int rb = 0; rb < 2; rb++)
#pragma unroll
            for (int cb = 0; cb < 4; cb++) {
                int col = (w * 4 + cb) * 16 + c15;
#pragma unroll
                for (int p = 0; p < 2; p++) {
                    Sb[sw_off(rb * 16 + q * 4 + 2 * p,     col)] = (short)(srp[rb][cb][p] & 0xFFFFu);
                    Sb[sw_off(rb * 16 + q * 4 + 2 * p + 1, col)] = (short)(srp[rb][cb][p] >> 16);
                    sreg[rb][cb][p] = srp[rb][cb][p];
                }
            }
        __syncthreads();   // B4: new S visible
    }

    // ---- out = S @ Wf + bf : 8 threads/row, vectorized LDS reads ----
    {
        int row = tid >> 3;
        int seg = tid & 7;
        float sum = 0.0f;
#pragma unroll
        for (int j = 0; j < 4; j++) {
            int ch = seg * 4 + j;
            bf16x8 sv = *(const bf16x8*)(Sb + row * 256 + (((ch ^ row) & 31) << 3));
            float4 wa = *(const float4*)(Wf + ch * 8);
            float4 wb = *(const float4*)(Wf + ch * 8 + 4);
            sum += bf2f(sv[0]) * wa.x + bf2f(sv[1]) * wa.y + bf2f(sv[2]) * wa.z + bf2f(sv[3]) * wa.w
                 + bf2f(sv[4]) * wb.x + bf2f(sv[5]) * wb.y + bf2f(sv[6]) * wb.z + bf2f(sv[7]) * wb.w;
        }
        sum += __shfl_down(sum, 4, 8);
        sum += __shfl_down(sum, 2, 8);
        sum += __shfl_down(sum, 1, 8);
        if (seg == 0) out[m0 + row] = sum + bfp[0];
    }
}

extern "C" void kernel_launch(void* const* d_in, const int* in_sizes, int n_in,
                              void* d_out, int out_size, void* d_ws, size_t ws_size,
                              hipStream_t stream) {
    const float* T  = (const float*)d_in[0];
    const float* X  = (const float*)d_in[1];
    const float* W0 = (const float*)d_in[2];
    const float* b0 = (const float*)d_in[3];
    const float* Uz = (const float*)d_in[4];
    const float* Ug = (const float*)d_in[5];
    const float* Ur = (const float*)d_in[6];
    const float* Uh = (const float*)d_in[7];
    const float* Wz = (const float*)d_in[8];
    const float* Wg = (const float*)d_in[9];
    const float* Wr = (const float*)d_in[10];
    const float* Wh = (const float*)d_in[11];
    const float* bz = (const float*)d_in[12];
    const float* bg = (const float*)d_in[13];
    const float* br = (const float*)d_in[14];
    const float* bh = (const float*)d_in[15];
    const float* Wf = (const float*)d_in[16];
    const float* bfp= (const float*)d_in[17];
    float* out = (float*)d_out;
    short* Wp = (short*)d_ws;           // 12*65536 bf16 = 1.5 MB
    const int N = in_sizes[0];

    pack_w<<<(12 * 65536) / 256, 256, 0, stream>>>(Wz, Wg, Wr, Wh, Wp);
    dgm_main<<<N / 32, 256, 0, stream>>>(T, X, W0, b0, Uz, Ug, Ur, Uh,
                                         bz, bg, br, bh, Wf, bfp, Wp, out);
}

// Round 5
// 547.742 us; speedup vs baseline: 3.4358x; 2.4902x over previous
//
#include <hip/hip_runtime.h>

// DGM forward, MI355X. bf16 MFMA 16x16x32, fp32 accum, fp32 tanh.
// R5: R4 structure with __launch_bounds__(256,2) — the ONLY bound that gives
//     VGPR=128 / no-spill on this compiler (R1 evidence; (256,4)/(512,4) => 64 VGPR + spill).
//     M=32/WG, 256 thr, wave w owns cols [w*64,w*64+64).
//     SRb eliminated via zs = Z*S_old trick -> LDS = Sb(16K)+S1b(16K)+eps = 33KB
//     -> 4 WGs/CU resource-limited (16 waves/CU) despite min-bound of 2.
//     sreg: packed bf16 register mirror of owned S elements.
//     Gate order Z, R, G(S1b-only) before B1; one f32 acc set live at a time.
//
// MFMA 16x16x32 layouts (ln = lane, q = ln>>4, c15 = ln&15):
//  A-frag: lane holds A[m=c15][k=kb*32+q*8+i], i=0..7
//  B-frag: lane holds B[k=kb*32+q*8+i][n=cblk*16+c15]
//  C/D:    lane holds C[row=q*4+ii][col=c15]
// W packed (d_ws) B-frag order per matrix: idx = (((cblk*8+kb)*64+ln)*8+i)
// LDS state swizzle: elem(r,k) -> r*256 + (((k>>3)^r)&31)*8 + (k&7)

typedef __attribute__((ext_vector_type(8))) short bf16x8;
typedef __attribute__((ext_vector_type(4))) float f32x4;

__device__ __forceinline__ short f2bf(float f) {
    unsigned u = __float_as_uint(f);
    unsigned r = (u + 0x7FFFu + ((u >> 16) & 1u)) >> 16;
    return (short)r;
}
__device__ __forceinline__ float bf2f(short h) {
    return __uint_as_float(((unsigned)(unsigned short)h) << 16);
}
__device__ __forceinline__ float fast_tanh(float x) {
    float e = __expf(2.0f * x);
    return 1.0f - 2.0f * __builtin_amdgcn_rcpf(e + 1.0f);
}
__device__ __forceinline__ int sw_off(int r, int k) {
    return r * 256 + ((((k >> 3) ^ r) & 31) << 3) + (k & 7);
}
__device__ __forceinline__ unsigned pk2(float a, float b) {
    return (unsigned)(unsigned short)f2bf(a) | ((unsigned)(unsigned short)f2bf(b) << 16);
}
__device__ __forceinline__ float upk(unsigned p, int hi) {
    return __uint_as_float(hi ? (p & 0xFFFF0000u) : (p << 16));
}

// ---------------- pack weights fp32 -> bf16, B-frag order ----------------
__global__ void pack_w(const float* __restrict__ Wz, const float* __restrict__ Wg,
                       const float* __restrict__ Wr, const float* __restrict__ Wh,
                       short* __restrict__ out) {
    int idx = blockIdx.x * 256 + threadIdx.x;   // 12*65536 threads
    int mat = idx >> 16;                        // 0..11 = l*4+g
    int e   = idx & 65535;
    int l = mat >> 2, g = mat & 3;
    int i  = e & 7;
    int ln = (e >> 3) & 63;
    int kb = (e >> 9) & 7;
    int c  = e >> 12;
    int k = kb * 32 + (ln >> 4) * 8 + i;
    int n = c * 16 + (ln & 15);
    const float* W = (g == 0) ? Wz : (g == 1) ? Wg : (g == 2) ? Wr : Wh;
    out[idx] = f2bf(W[l * 65536 + k * 256 + n]);
}

// ---------------- one gate GEMM: acc = bias + X@U + In@W ----------------
__device__ __forceinline__ void gate_gemm(const short* __restrict__ In,   // LDS [32][256] swizzled
                                          const short* __restrict__ Wm,   // packed bf16 65536
                                          const float* __restrict__ U,    // [2][256] fp32
                                          const float* __restrict__ bias, // [256]
                                          const float2* __restrict__ txS, // LDS [32]
                                          int q, int c15, int w,
                                          f32x4 acc[2][4]) {
    float2 tx[8];
#pragma unroll
    for (int rb = 0; rb < 2; rb++)
#pragma unroll
        for (int ii = 0; ii < 4; ii++) tx[rb * 4 + ii] = txS[rb * 16 + q * 4 + ii];
#pragma unroll
    for (int cb = 0; cb < 4; cb++) {
        int col = (w * 4 + cb) * 16 + c15;
        float u0 = U[col], u1 = U[256 + col], bb = bias[col];
#pragma unroll
        for (int rb = 0; rb < 2; rb++)
#pragma unroll
            for (int ii = 0; ii < 4; ii++)
                acc[rb][cb][ii] = bb + tx[rb * 4 + ii].x * u0 + tx[rb * 4 + ii].y * u1;
    }
#pragma unroll
    for (int kb = 0; kb < 8; kb++) {
        bf16x8 a[2];
#pragma unroll
        for (int rb = 0; rb < 2; rb++) {
            int r = rb * 16 + c15;
            a[rb] = *(const bf16x8*)(In + r * 256 + ((((kb * 4 + q) ^ r) & 31) << 3));
        }
#pragma unroll
        for (int cb = 0; cb < 4; cb++) {
            bf16x8 b = *(const bf16x8*)(Wm + ((((w * 4 + cb) * 8 + kb) * 64 + (q * 16 + c15)) << 3));
#pragma unroll
            for (int rb = 0; rb < 2; rb++)
                acc[rb][cb] = __builtin_amdgcn_mfma_f32_16x16x32_bf16(a[rb], b, acc[rb][cb], 0, 0, 0);
        }
    }
}

// ---------------- main kernel: 32 rows/WG, 256 threads ----------------
__global__ __launch_bounds__(256, 2)
void dgm_main(const float* __restrict__ T, const float* __restrict__ X,
              const float* __restrict__ W0, const float* __restrict__ b0,
              const float* __restrict__ Uz, const float* __restrict__ Ug,
              const float* __restrict__ Ur, const float* __restrict__ Uh,
              const float* __restrict__ bz, const float* __restrict__ bg,
              const float* __restrict__ br, const float* __restrict__ bh,
              const float* __restrict__ Wf, const float* __restrict__ bfp,
              const short* __restrict__ Wp, float* __restrict__ out) {
    __shared__ __align__(16) short Sb[8192];    // 16 KB: S (holds S*R mid-layer)
    __shared__ __align__(16) short S1b[8192];   // 16 KB: S1, immutable
    __shared__ float2 txS[32];

    const int tid = threadIdx.x;
    const int w   = tid >> 6;        // 0..3
    const int ln  = tid & 63;
    const int q   = ln >> 4;
    const int c15 = ln & 15;
    const int m0  = blockIdx.x * 32;

    if (tid < 32) txS[tid] = make_float2(T[m0 + tid], X[m0 + tid]);
    __syncthreads();

    // ---- S1 = tanh(X@W0 + b0); S = S1.  One column per thread, 32 rows. ----
    {
        float w00 = W0[tid], w01 = W0[256 + tid], bb = b0[tid];
#pragma unroll 4
        for (int r = 0; r < 32; r++) {
            float2 tx = txS[r];
            short v = f2bf(fast_tanh(tx.x * w00 + tx.y * w01 + bb));
            int off = sw_off(r, tid);
            S1b[off] = v;
            Sb[off]  = v;
        }
    }
    __syncthreads();

    // register mirror of this thread's owned S elements (C-layout), packed bf16
    unsigned sreg[2][4][2];
#pragma unroll
    for (int rb = 0; rb < 2; rb++)
#pragma unroll
        for (int cb = 0; cb < 4; cb++) {
            int col = (w * 4 + cb) * 16 + c15;
#pragma unroll
            for (int p = 0; p < 2; p++) {
                unsigned lo = (unsigned short)Sb[sw_off(rb * 16 + q * 4 + 2 * p,     col)];
                unsigned hi = (unsigned short)Sb[sw_off(rb * 16 + q * 4 + 2 * p + 1, col)];
                sreg[rb][cb][p] = lo | (hi << 16);
            }
        }

    // ---- layers ----
    for (int l = 0; l < 3; l++) {
        const short* Wzp = Wp + (l * 4 + 0) * 65536;
        const short* Wgp = Wp + (l * 4 + 1) * 65536;
        const short* Wrp = Wp + (l * 4 + 2) * 65536;
        const short* Whp = Wp + (l * 4 + 3) * 65536;

        f32x4 acc[2][4];
        unsigned zsp[2][4][2], srp[2][4][2], gmp[2][4][2];

        // Z gate: zs = tanh(Z)*S_old
        gate_gemm(Sb, Wzp, Uz + l * 512, bz + l * 256, txS, q, c15, w, acc);
#pragma unroll
        for (int rb = 0; rb < 2; rb++)
#pragma unroll
            for (int cb = 0; cb < 4; cb++)
#pragma unroll
                for (int p = 0; p < 2; p++)
                    zsp[rb][cb][p] = pk2(
                        fast_tanh(acc[rb][cb][2 * p])     * upk(sreg[rb][cb][p], 0),
                        fast_tanh(acc[rb][cb][2 * p + 1]) * upk(sreg[rb][cb][p], 1));

        // R gate: sr = S_old*tanh(R)
        gate_gemm(Sb, Wrp, Ur + l * 512, br + l * 256, txS, q, c15, w, acc);
#pragma unroll
        for (int rb = 0; rb < 2; rb++)
#pragma unroll
            for (int cb = 0; cb < 4; cb++)
#pragma unroll
                for (int p = 0; p < 2; p++)
                    srp[rb][cb][p] = pk2(
                        fast_tanh(acc[rb][cb][2 * p])     * upk(sreg[rb][cb][p], 0),
                        fast_tanh(acc[rb][cb][2 * p + 1]) * upk(sreg[rb][cb][p], 1));

        // G gate (reads only S1b)
        gate_gemm(S1b, Wgp, Ug + l * 512, bg + l * 256, txS, q, c15, w, acc);
#pragma unroll
        for (int rb = 0; rb < 2; rb++)
#pragma unroll
            for (int cb = 0; cb < 4; cb++)
#pragma unroll
                for (int p = 0; p < 2; p++)
                    gmp[rb][cb][p] = pk2(1.0f - fast_tanh(acc[rb][cb][2 * p]),
                                         1.0f - fast_tanh(acc[rb][cb][2 * p + 1]));

        __syncthreads();   // B1: all Sb reads (Z,R A-frags) done
#pragma unroll
        for (int rb = 0; rb < 2; rb++)
#pragma unroll
            for (int cb = 0; cb < 4; cb++) {
                int col = (w * 4 + cb) * 16 + c15;
#pragma unroll
                for (int p = 0; p < 2; p++) {
                    Sb[sw_off(rb * 16 + q * 4 + 2 * p,     col)] = (short)(srp[rb][cb][p] & 0xFFFFu);
                    Sb[sw_off(rb * 16 + q * 4 + 2 * p + 1, col)] = (short)(srp[rb][cb][p] >> 16);
                }
            }
        __syncthreads();   // B2: Sb = S*R visible

        // H gate (reads Sb = S*R)
        gate_gemm(Sb, Whp, Uh + l * 512, bh + l * 256, txS, q, c15, w, acc);

        // S_new = (1-G)*tanh(H) + zs  (no Sb access here)
#pragma unroll
        for (int rb = 0; rb < 2; rb++)
#pragma unroll
            for (int cb = 0; cb < 4; cb++)
#pragma unroll
                for (int p = 0; p < 2; p++) {
                    float sn0 = upk(gmp[rb][cb][p], 0) * fast_tanh(acc[rb][cb][2 * p])
                              + upk(zsp[rb][cb][p], 0);
                    float sn1 = upk(gmp[rb][cb][p], 1) * fast_tanh(acc[rb][cb][2 * p + 1])
                              + upk(zsp[rb][cb][p], 1);
                    srp[rb][cb][p] = pk2(sn0, sn1);
                }

        __syncthreads();   // B3: all H A-frag reads of Sb done
#pragma unroll
        for (int rb = 0; rb < 2; rb++)
#pragma unroll
            for (int cb = 0; cb < 4; cb++) {
                int col = (w * 4 + cb) * 16 + c15;
#pragma unroll
                for (int p = 0; p < 2; p++) {
                    Sb[sw_off(rb * 16 + q * 4 + 2 * p,     col)] = (short)(srp[rb][cb][p] & 0xFFFFu);
                    Sb[sw_off(rb * 16 + q * 4 + 2 * p + 1, col)] = (short)(srp[rb][cb][p] >> 16);
                    sreg[rb][cb][p] = srp[rb][cb][p];
                }
            }
        __syncthreads();   // B4: new S visible
    }

    // ---- out = S @ Wf + bf : 8 threads/row, vectorized LDS reads ----
    {
        int row = tid >> 3;
        int seg = tid & 7;
        float sum = 0.0f;
#pragma unroll
        for (int j = 0; j < 4; j++) {
            int ch = seg * 4 + j;
            bf16x8 sv = *(const bf16x8*)(Sb + row * 256 + (((ch ^ row) & 31) << 3));
            float4 wa = *(const float4*)(Wf + ch * 8);
            float4 wb = *(const float4*)(Wf + ch * 8 + 4);
            sum += bf2f(sv[0]) * wa.x + bf2f(sv[1]) * wa.y + bf2f(sv[2]) * wa.z + bf2f(sv[3]) * wa.w
                 + bf2f(sv[4]) * wb.x + bf2f(sv[5]) * wb.y + bf2f(sv[6]) * wb.z + bf2f(sv[7]) * wb.w;
        }
        sum += __shfl_down(sum, 4, 8);
        sum += __shfl_down(sum, 2, 8);
        sum += __shfl_down(sum, 1, 8);
        if (seg == 0) out[m0 + row] = sum + bfp[0];
    }
}

extern "C" void kernel_launch(void* const* d_in, const int* in_sizes, int n_in,
                              void* d_out, int out_size, void* d_ws, size_t ws_size,
                              hipStream_t stream) {
    const float* T  = (const float*)d_in[0];
    const float* X  = (const float*)d_in[1];
    const float* W0 = (const float*)d_in[2];
    const float* b0 = (const float*)d_in[3];
    const float* Uz = (const float*)d_in[4];
    const float* Ug = (const float*)d_in[5];
    const float* Ur = (const float*)d_in[6];
    const float* Uh = (const float*)d_in[7];
    const float* Wz = (const float*)d_in[8];
    const float* Wg = (const float*)d_in[9];
    const float* Wr = (const float*)d_in[10];
    const float* Wh = (const float*)d_in[11];
    const float* bz = (const float*)d_in[12];
    const float* bg = (const float*)d_in[13];
    const float* br = (const float*)d_in[14];
    const float* bh = (const float*)d_in[15];
    const float* Wf = (const float*)d_in[16];
    const float* bfp= (const float*)d_in[17];
    float* out = (float*)d_out;
    short* Wp = (short*)d_ws;           // 12*65536 bf16 = 1.5 MB
    const int N = in_sizes[0];

    pack_w<<<(12 * 65536) / 256, 256, 0, stream>>>(Wz, Wg, Wr, Wh, Wp);
    dgm_main<<<N / 32, 256, 0, stream>>>(T, X, W0, b0, Uz, Ug, Ur, Uh,
                                         bz, bg, br, bh, Wf, bfp, Wp, out);
}